// Round 1
// baseline (198.672 us; speedup 1.0000x reference)
//
#include <hip/hip_runtime.h>
#include <cstddef>
#include <cstdint>

// Problem constants (fixed by the reference):
//   B=256 batches, S=128*128=16384, R=16, N=6 cores.
//   V_k[b,d,e] = sum_s z[b,s] * core_k[d,s,e]   (k=1..5)   <- 8.7 GFLOP, dominant
//   W[b]      = V1[b] @ V2[b] @ V3[b] @ V4[b] @ V5[b]      <- tiny
//   out[b,s]  = sum_d core0[0,s,d] * W[b,d]                <- memory-bound
namespace {
constexpr int kB = 256;
constexpr int kS = 16384;
constexpr int kNCol = 1040;   // 4 cores * 256 cols + 16 cols (core5)
constexpr int kKS = 32;       // K-slice per LDS stage
}

// ---------------------------------------------------------------------------
// Kernel 1: V = z @ G  (split-K partials into vp[split][1040][256])
// grid (17, 4, splitk), block 256.
//   ct 0..15 : core (1+ct/4), d-slice (ct%4)*4..+3  -> 64 columns (col = d*16+e)
//   ct == 16 : core5 -> 16 columns (col = 1024+d)
// Block tile: 64 batches x 64 cols (ct<16) over K-chunk kc.
// Per-thread 4x4 outer product; register-prefetch of next stage's global data.
// ---------------------------------------------------------------------------
__global__ __launch_bounds__(256, 4) void fttv_gemm(
    const float* __restrict__ z,
    const float* __restrict__ c1, const float* __restrict__ c2,
    const float* __restrict__ c3, const float* __restrict__ c4,
    const float* __restrict__ c5,
    float* __restrict__ vp, int kc)
{
    const int ct = blockIdx.x;
    const int b0 = blockIdx.y * 64;
    const int sbeg = blockIdx.z * kc;
    const int tid = threadIdx.x;
    const int ty = tid >> 4, tx = tid & 15;

    __shared__ float zs[kKS][68];        // zs[s][b], pad 68 -> <=4-way write, clean reads
    __shared__ float bs[4][kKS + 1][16]; // bs[dloc][s][e], pad row -> 2-way reads

    // z staging geometry: 64 b x 32 s tile = 512 float4; thread -> 2 float4
    const int zr_r = tid >> 3;        // 0..31  (batch row within tile, +32 for 2nd)
    const int zr_c = (tid & 7) * 4;   // s offset within 32
    const float* zp = z + (size_t)(b0 + zr_r) * kS + zr_c;

    if (ct < 16) {
        const float* core = (ct < 4) ? c1 : (ct < 8) ? c2 : (ct < 12) ? c3 : c4;
        const float* bsrc = core + (size_t)((ct & 3) * 4) * ((size_t)kS * 16);
        // B staging: 4 d-slices x 32 s x 16 e = 512 float4; thread -> 2 float4
        const int b_d   = tid >> 7;        // 0..1 (+2 for 2nd load)
        const int b_rem = tid & 127;
        const int b_s   = b_rem >> 2;      // 0..31
        const int b_e   = (b_rem & 3) * 4;
        const float* bp = bsrc + (size_t)b_d * ((size_t)kS * 16) + (size_t)b_s * 16 + b_e;

        float4 zr0 = *reinterpret_cast<const float4*>(zp + sbeg);
        float4 zr1 = *reinterpret_cast<const float4*>(zp + (size_t)32 * kS + sbeg);
        float4 br0 = *reinterpret_cast<const float4*>(bp + (size_t)sbeg * 16);
        float4 br1 = *reinterpret_cast<const float4*>(bp + (size_t)2 * kS * 16 + (size_t)sbeg * 16);

        float acc[4][4];
        #pragma unroll
        for (int i = 0; i < 4; ++i)
            #pragma unroll
            for (int j = 0; j < 4; ++j) acc[i][j] = 0.f;

        for (int sb = 0; sb < kc; sb += kKS) {
            // commit staged registers to LDS
            zs[zr_c + 0][zr_r] = zr0.x;
            zs[zr_c + 1][zr_r] = zr0.y;
            zs[zr_c + 2][zr_r] = zr0.z;
            zs[zr_c + 3][zr_r] = zr0.w;
            zs[zr_c + 0][zr_r + 32] = zr1.x;
            zs[zr_c + 1][zr_r + 32] = zr1.y;
            zs[zr_c + 2][zr_r + 32] = zr1.z;
            zs[zr_c + 3][zr_r + 32] = zr1.w;
            *reinterpret_cast<float4*>(&bs[b_d][b_s][b_e]) = br0;
            *reinterpret_cast<float4*>(&bs[b_d + 2][b_s][b_e]) = br1;
            __syncthreads();
            // prefetch next stage (overlaps with compute below)
            if (sb + kKS < kc) {
                const int sn = sbeg + sb + kKS;
                zr0 = *reinterpret_cast<const float4*>(zp + sn);
                zr1 = *reinterpret_cast<const float4*>(zp + (size_t)32 * kS + sn);
                br0 = *reinterpret_cast<const float4*>(bp + (size_t)sn * 16);
                br1 = *reinterpret_cast<const float4*>(bp + (size_t)2 * kS * 16 + (size_t)sn * 16);
            }
            #pragma unroll
            for (int ss = 0; ss < kKS; ++ss) {
                float zv[4], bv[4];
                *reinterpret_cast<float4*>(zv) =
                    *reinterpret_cast<const float4*>(&zs[ss][ty * 4]);
                *reinterpret_cast<float4*>(bv) =
                    *reinterpret_cast<const float4*>(&bs[tx >> 2][ss][(tx & 3) * 4]);
                #pragma unroll
                for (int i = 0; i < 4; ++i)
                    #pragma unroll
                    for (int j = 0; j < 4; ++j) acc[i][j] += zv[i] * bv[j];
            }
            __syncthreads();
        }
        #pragma unroll
        for (int j = 0; j < 4; ++j) {
            const int col = ct * 64 + tx * 4 + j;
            float4 o;
            o.x = acc[0][j]; o.y = acc[1][j]; o.z = acc[2][j]; o.w = acc[3][j];
            *reinterpret_cast<float4*>(
                vp + ((size_t)blockIdx.z * kNCol + col) * kB + b0 + ty * 4) = o;
        }
    } else {
        // core5: 16 columns; bs[0][s][d]
        const int b_d = tid >> 3;        // d (valid for tid<128)
        const int b_c = (tid & 7) * 4;   // s offset
        const float* cp = c5 + (size_t)b_d * kS + b_c;

        float4 zr0 = *reinterpret_cast<const float4*>(zp + sbeg);
        float4 zr1 = *reinterpret_cast<const float4*>(zp + (size_t)32 * kS + sbeg);
        float4 br0 = make_float4(0.f, 0.f, 0.f, 0.f);
        if (tid < 128) br0 = *reinterpret_cast<const float4*>(cp + sbeg);

        float acc[4] = {0.f, 0.f, 0.f, 0.f};
        for (int sb = 0; sb < kc; sb += kKS) {
            zs[zr_c + 0][zr_r] = zr0.x;
            zs[zr_c + 1][zr_r] = zr0.y;
            zs[zr_c + 2][zr_r] = zr0.z;
            zs[zr_c + 3][zr_r] = zr0.w;
            zs[zr_c + 0][zr_r + 32] = zr1.x;
            zs[zr_c + 1][zr_r + 32] = zr1.y;
            zs[zr_c + 2][zr_r + 32] = zr1.z;
            zs[zr_c + 3][zr_r + 32] = zr1.w;
            if (tid < 128) {
                bs[0][b_c + 0][b_d] = br0.x;
                bs[0][b_c + 1][b_d] = br0.y;
                bs[0][b_c + 2][b_d] = br0.z;
                bs[0][b_c + 3][b_d] = br0.w;
            }
            __syncthreads();
            if (sb + kKS < kc) {
                const int sn = sbeg + sb + kKS;
                zr0 = *reinterpret_cast<const float4*>(zp + sn);
                zr1 = *reinterpret_cast<const float4*>(zp + (size_t)32 * kS + sn);
                if (tid < 128) br0 = *reinterpret_cast<const float4*>(cp + sn);
            }
            #pragma unroll
            for (int ss = 0; ss < kKS; ++ss) {
                float zv[4];
                *reinterpret_cast<float4*>(zv) =
                    *reinterpret_cast<const float4*>(&zs[ss][ty * 4]);
                const float bv = bs[0][ss][tx];
                #pragma unroll
                for (int i = 0; i < 4; ++i) acc[i] += zv[i] * bv;
            }
            __syncthreads();
        }
        const int col = 1024 + tx;
        float4 o;
        o.x = acc[0]; o.y = acc[1]; o.z = acc[2]; o.w = acc[3];
        *reinterpret_cast<float4*>(
            vp + ((size_t)blockIdx.z * kNCol + col) * kB + b0 + ty * 4) = o;
    }
}

// ---------------------------------------------------------------------------
// Kernel 2: reduce split-K partials: v[col][b] = sum_k vp[k][col][b]
// ---------------------------------------------------------------------------
__global__ void fttv_reduce(const float* __restrict__ vp, float* __restrict__ v,
                            int splitk)
{
    const int idx = blockIdx.x * 256 + threadIdx.x;   // grid exactly covers 1040*256
    float s = 0.f;
    for (int k = 0; k < splitk; ++k) s += vp[(size_t)k * kNCol * kB + idx];
    v[idx] = s;
}

// ---------------------------------------------------------------------------
// Kernel 3: W[b] = V1[b] @ V2[b] @ V3[b] @ V4[b] @ V5col[b]  (right fold)
// one block (64 thr) per batch; lanes d=lane&15 hold u[d].
// ---------------------------------------------------------------------------
__global__ void fttv_chain(const float* __restrict__ v, float* __restrict__ w)
{
    const int b = blockIdx.x;
    const int lane = threadIdx.x;
    const int d = lane & 15;
    float u = v[(size_t)(1024 + d) * kB + b];          // V5 column
    #pragma unroll
    for (int k = 4; k >= 1; --k) {
        float nu = 0.f;
        #pragma unroll
        for (int e = 0; e < 16; ++e) {
            const float ue = __shfl(u, e, 16);
            nu += v[(size_t)((k - 1) * 256 + d * 16 + e) * kB + b] * ue;
        }
        u = nu;
    }
    if (lane < 16) w[b * 16 + d] = u;
}

// ---------------------------------------------------------------------------
// Kernel 4: out[b,s] = sum_d core0[s,d] * W[b,d]
// grid 256 = 64 s-chunks x 4 batch-quarters; thread owns one s (F0 row in regs)
// ---------------------------------------------------------------------------
__global__ __launch_bounds__(256) void fttv_out(
    const float* __restrict__ c0, const float* __restrict__ w,
    float* __restrict__ out)
{
    __shared__ float wl[64][16];
    const int sc = blockIdx.x & 63;
    const int bq = blockIdx.x >> 6;
    const int tid = threadIdx.x;
    const int s = sc * 256 + tid;
    float f0[16];
    #pragma unroll
    for (int q = 0; q < 4; ++q) {
        *reinterpret_cast<float4*>(&f0[q * 4]) =
            *reinterpret_cast<const float4*>(c0 + (size_t)s * 16 + q * 4);
    }
    *reinterpret_cast<float4*>(&wl[0][0] + tid * 4) =
        *reinterpret_cast<const float4*>(w + bq * 1024 + tid * 4);
    __syncthreads();
    for (int bb = 0; bb < 64; ++bb) {
        float a = 0.f;
        #pragma unroll
        for (int d = 0; d < 16; ++d) a += f0[d] * wl[bb][d];
        out[(size_t)(bq * 64 + bb) * kS + s] = a;
    }
}

// ---------------------------------------------------------------------------
extern "C" void kernel_launch(void* const* d_in, const int* in_sizes, int n_in,
                              void* d_out, int out_size, void* d_ws, size_t ws_size,
                              hipStream_t stream)
{
    (void)in_sizes; (void)n_in; (void)out_size;
    const float* z  = (const float*)d_in[0];
    const float* c0 = (const float*)d_in[1];
    const float* c1 = (const float*)d_in[2];
    const float* c2 = (const float*)d_in[3];
    const float* c3 = (const float*)d_in[4];
    const float* c4 = (const float*)d_in[5];
    const float* c5 = (const float*)d_in[6];
    float* out = (float*)d_out;
    float* ws  = (float*)d_ws;

    // workspace: vp[splitk][1040][256] | v[1040][256] | w[256][16]
    int splitk = 16;
    while (splitk > 1 &&
           ((size_t)(splitk + 1) * kNCol * kB + (size_t)kB * 16) * sizeof(float) > ws_size)
        splitk >>= 1;
    const int kc = kS / splitk;

    float* vp = ws;
    float* v  = vp + (size_t)splitk * kNCol * kB;
    float* w  = v + (size_t)kNCol * kB;

    fttv_gemm<<<dim3(17, 4, splitk), 256, 0, stream>>>(z, c1, c2, c3, c4, c5, vp, kc);
    fttv_reduce<<<dim3((kNCol * kB) / 256), 256, 0, stream>>>(vp, v, splitk);
    fttv_chain<<<dim3(kB), 64, 0, stream>>>(v, w);
    fttv_out<<<dim3(256), 256, 0, stream>>>(c0, w, out);
}

// Round 2
// 73.113 us; speedup vs baseline: 2.7173x; 2.7173x over previous
//
#include <hip/hip_runtime.h>
#include <cstddef>
#include <cstdint>

// B=256 batches, S=16384, R=16, N=6 cores.
//   V_k[b,(d,e)] = sum_s z[b,s]*core_k[d,s,e]  (k=1..5)  -> bf16-split MFMA GEMM
//   W[b] = V1..V5 chain (tiny), out[b,s] = sum_d c0[s,d]*W[b,d] (mem-bound)
namespace {
constexpr int kB = 256;
constexpr int kS = 16384;
constexpr int kNCol = 1040;   // 4 cores * 256 + 16 (core5)
constexpr int BK = 64;        // K per LDS stage
}

using short8 = __attribute__((ext_vector_type(8))) short;   // 8 bf16 = 4 VGPR
using f32x4  = __attribute__((ext_vector_type(4))) float;

// truncation split: x ~= hi + lo, hi/lo bf16 bit patterns (RNE not needed at
// this accuracy; trunc keeps conversion ~3 VALU/elem)
__device__ __forceinline__ void cvt4(float x0, float x1, float x2, float x3,
                                     ushort4& h, ushort4& l) {
    uint32_t u0 = __float_as_uint(x0), u1 = __float_as_uint(x1),
             u2 = __float_as_uint(x2), u3 = __float_as_uint(x3);
    h.x = (unsigned short)(u0 >> 16); h.y = (unsigned short)(u1 >> 16);
    h.z = (unsigned short)(u2 >> 16); h.w = (unsigned short)(u3 >> 16);
    float r0 = x0 - __uint_as_float(u0 & 0xffff0000u);
    float r1 = x1 - __uint_as_float(u1 & 0xffff0000u);
    float r2 = x2 - __uint_as_float(u2 & 0xffff0000u);
    float r3 = x3 - __uint_as_float(u3 & 0xffff0000u);
    l.x = (unsigned short)(__float_as_uint(r0) >> 16);
    l.y = (unsigned short)(__float_as_uint(r1) >> 16);
    l.z = (unsigned short)(__float_as_uint(r2) >> 16);
    l.w = (unsigned short)(__float_as_uint(r3) >> 16);
}

// ---------------------------------------------------------------------------
// MFMA split-bf16 GEMM: vp[sk][col][b] partial of z @ G over k-chunk sk.
// grid flat = 34*splitk (2 m-tiles x 17 col-tiles x splitk), 256 thr.
// Block tile 128b x 64n, BK=64; 4 waves of 64x32 (ct<16) / 32x16 (ct==16).
// LDS planes: As[hi/lo][128][64], Bs[hi/lo][64][64] bf16, XOR-swizzled
// (ushort idx: k ^ ((row&7)<<3)) -> conflict-free ds_read_b128 frags.
// ---------------------------------------------------------------------------
__global__ __launch_bounds__(256, 2) void fttv_gemm_mfma(
    const float* __restrict__ z,
    const float* __restrict__ c1, const float* __restrict__ c2,
    const float* __restrict__ c3, const float* __restrict__ c4,
    const float* __restrict__ c5,
    float* __restrict__ vp, int kc)
{
    __shared__ unsigned short As[2 * 128 * 64];   // 32 KB
    __shared__ unsigned short Bs[2 * 64 * 64];    // 16 KB

    // bijective XCD swizzle (m204): consecutive v share one XCD ->
    // same-sk blocks (same z chunk + shared B chunks) get L2 locality.
    const int nwg = gridDim.x;
    const int q = nwg >> 3, r = nwg & 7;
    const int xcd = blockIdx.x & 7, rest = blockIdx.x >> 3;
    const int v = (xcd < r ? xcd * (q + 1) : r * (q + 1) + (xcd - r) * q) + rest;
    const int sk = v / 34;
    const int rem = v - sk * 34;
    const int mt = rem / 17;
    const int ct = rem - mt * 17;

    const int tid = threadIdx.x;
    const int b0 = mt * 128;
    const int sbeg = sk * kc;

    // A staging: thread -> rows (tid>>4)+16p (p=0..7), k-quad (tid&15)*4
    const int ar = tid >> 4;
    const int ak = (tid & 15) * 4;
    const float* zb = z + (size_t)(b0 + ar) * kS + sbeg + ak;

    const int l = tid & 63, w = tid >> 6;
    const int lr = l & 15, lk = (l >> 4) * 8, swz = (l & 7) << 3;

    f32x4 acc[4][2];
    #pragma unroll
    for (int i = 0; i < 4; ++i)
        #pragma unroll
        for (int j = 0; j < 2; ++j) acc[i][j] = (f32x4){0.f, 0.f, 0.f, 0.f};

    if (ct < 16) {
        const int ci = ct >> 2;
        const float* cp = (ci == 0 ? c1 : ci == 1 ? c2 : ci == 2 ? c3 : c4)
                        + (size_t)(ct & 3) * 4 * ((size_t)kS * 16);
        // B staging: thread -> 4x4 subtile (k0=(tid&15)*4, n0=(tid>>4)*4)
        const int bk0 = (tid & 15) * 4;
        const int bn0 = (tid >> 4) * 4;
        const float* bp = cp + (size_t)(bn0 >> 4) * ((size_t)kS * 16)
                        + (size_t)sbeg * 16 + (bn0 & 15);
        const int moff = (w >> 1) * 64, noff = (w & 1) * 32;

        float4 za[8], bb[4];
        #pragma unroll
        for (int p = 0; p < 8; ++p)
            za[p] = *reinterpret_cast<const float4*>(zb + (size_t)16 * p * kS);
        #pragma unroll
        for (int i = 0; i < 4; ++i)
            bb[i] = *reinterpret_cast<const float4*>(bp + (size_t)(bk0 + i) * 16);

        for (int sb = 0; sb < kc; sb += BK) {
            #pragma unroll
            for (int p = 0; p < 8; ++p) {
                const int rr = ar + 16 * p;
                ushort4 h, lo;
                cvt4(za[p].x, za[p].y, za[p].z, za[p].w, h, lo);
                const int idx = rr * 64 + (ak ^ ((rr & 7) << 3));
                *reinterpret_cast<ushort4*>(&As[idx]) = h;
                *reinterpret_cast<ushort4*>(&As[8192 + idx]) = lo;
            }
            #pragma unroll
            for (int j = 0; j < 4; ++j) {
                const int n = bn0 + j;
                ushort4 h, lo;
                cvt4(reinterpret_cast<const float*>(&bb[0])[j],
                     reinterpret_cast<const float*>(&bb[1])[j],
                     reinterpret_cast<const float*>(&bb[2])[j],
                     reinterpret_cast<const float*>(&bb[3])[j], h, lo);
                const int idx = n * 64 + (bk0 ^ ((n & 7) << 3));
                *reinterpret_cast<ushort4*>(&Bs[idx]) = h;
                *reinterpret_cast<ushort4*>(&Bs[4096 + idx]) = lo;
            }
            __syncthreads();
            if (sb + BK < kc) {   // prefetch next stage under MFMA phase
                const int sn = sb + BK;
                #pragma unroll
                for (int p = 0; p < 8; ++p)
                    za[p] = *reinterpret_cast<const float4*>(zb + (size_t)16 * p * kS + sn);
                #pragma unroll
                for (int i = 0; i < 4; ++i)
                    bb[i] = *reinterpret_cast<const float4*>(bp + (size_t)(sn + bk0 + i) * 16);
            }
            #pragma unroll
            for (int kb = 0; kb < 2; ++kb) {
                const int kk = (kb * 32 + lk) ^ swz;
                short8 ah[4], al[4], bh[2], bl[2];
                #pragma unroll
                for (int fm = 0; fm < 4; ++fm) {
                    const int row = moff + fm * 16 + lr;
                    ah[fm] = *reinterpret_cast<const short8*>(&As[row * 64 + kk]);
                    al[fm] = *reinterpret_cast<const short8*>(&As[8192 + row * 64 + kk]);
                }
                #pragma unroll
                for (int fn = 0; fn < 2; ++fn) {
                    const int col = noff + fn * 16 + lr;
                    bh[fn] = *reinterpret_cast<const short8*>(&Bs[col * 64 + kk]);
                    bl[fn] = *reinterpret_cast<const short8*>(&Bs[4096 + col * 64 + kk]);
                }
                #pragma unroll
                for (int fm = 0; fm < 4; ++fm)
                    #pragma unroll
                    for (int fn = 0; fn < 2; ++fn) {
                        acc[fm][fn] = __builtin_amdgcn_mfma_f32_16x16x32_bf16(
                            ah[fm], bh[fn], acc[fm][fn], 0, 0, 0);
                        acc[fm][fn] = __builtin_amdgcn_mfma_f32_16x16x32_bf16(
                            ah[fm], bl[fn], acc[fm][fn], 0, 0, 0);
                        acc[fm][fn] = __builtin_amdgcn_mfma_f32_16x16x32_bf16(
                            al[fm], bh[fn], acc[fm][fn], 0, 0, 0);
                    }
            }
            __syncthreads();
        }
        #pragma unroll
        for (int fm = 0; fm < 4; ++fm)
            #pragma unroll
            for (int fn = 0; fn < 2; ++fn) {
                const int col = ct * 64 + noff + fn * 16 + lr;
                const int brow = b0 + moff + fm * 16 + (l >> 4) * 4;
                *reinterpret_cast<f32x4*>(
                    vp + ((size_t)sk * kNCol + col) * kB + brow) = acc[fm][fn];
            }
    } else {
        // core5 runt: B tile 64k x 16n; waves -> 32x16 each (moff = w*32)
        const int bn = tid & 15;
        const int bk0 = (tid >> 4) * 4;
        const float* bp = c5 + (size_t)bn * kS + sbeg + bk0;
        const int moff = w * 32;

        float4 za[8], bb;
        #pragma unroll
        for (int p = 0; p < 8; ++p)
            za[p] = *reinterpret_cast<const float4*>(zb + (size_t)16 * p * kS);
        bb = *reinterpret_cast<const float4*>(bp);

        for (int sb = 0; sb < kc; sb += BK) {
            #pragma unroll
            for (int p = 0; p < 8; ++p) {
                const int rr = ar + 16 * p;
                ushort4 h, lo;
                cvt4(za[p].x, za[p].y, za[p].z, za[p].w, h, lo);
                const int idx = rr * 64 + (ak ^ ((rr & 7) << 3));
                *reinterpret_cast<ushort4*>(&As[idx]) = h;
                *reinterpret_cast<ushort4*>(&As[8192 + idx]) = lo;
            }
            {
                ushort4 h, lo;
                cvt4(bb.x, bb.y, bb.z, bb.w, h, lo);
                const int idx = bn * 64 + (bk0 ^ ((bn & 7) << 3));
                *reinterpret_cast<ushort4*>(&Bs[idx]) = h;
                *reinterpret_cast<ushort4*>(&Bs[4096 + idx]) = lo;
            }
            __syncthreads();
            if (sb + BK < kc) {
                const int sn = sb + BK;
                #pragma unroll
                for (int p = 0; p < 8; ++p)
                    za[p] = *reinterpret_cast<const float4*>(zb + (size_t)16 * p * kS + sn);
                bb = *reinterpret_cast<const float4*>(bp + sn);
            }
            #pragma unroll
            for (int kb = 0; kb < 2; ++kb) {
                const int kk = (kb * 32 + lk) ^ swz;
                short8 ah[2], al[2], bh, bl;
                #pragma unroll
                for (int fm = 0; fm < 2; ++fm) {
                    const int row = moff + fm * 16 + lr;
                    ah[fm] = *reinterpret_cast<const short8*>(&As[row * 64 + kk]);
                    al[fm] = *reinterpret_cast<const short8*>(&As[8192 + row * 64 + kk]);
                }
                bh = *reinterpret_cast<const short8*>(&Bs[lr * 64 + kk]);
                bl = *reinterpret_cast<const short8*>(&Bs[4096 + lr * 64 + kk]);
                #pragma unroll
                for (int fm = 0; fm < 2; ++fm) {
                    acc[fm][0] = __builtin_amdgcn_mfma_f32_16x16x32_bf16(
                        ah[fm], bh, acc[fm][0], 0, 0, 0);
                    acc[fm][0] = __builtin_amdgcn_mfma_f32_16x16x32_bf16(
                        ah[fm], bl, acc[fm][0], 0, 0, 0);
                    acc[fm][0] = __builtin_amdgcn_mfma_f32_16x16x32_bf16(
                        al[fm], bh, acc[fm][0], 0, 0, 0);
                }
            }
            __syncthreads();
        }
        #pragma unroll
        for (int fm = 0; fm < 2; ++fm) {
            const int col = 1024 + lr;
            const int brow = b0 + moff + fm * 16 + (l >> 4) * 4;
            *reinterpret_cast<f32x4*>(
                vp + ((size_t)sk * kNCol + col) * kB + brow) = acc[fm][0];
        }
    }
}

// ---------------------------------------------------------------------------
__global__ void fttv_reduce(const float* __restrict__ vp, float* __restrict__ v,
                            int splitk)
{
    const int idx = blockIdx.x * 256 + threadIdx.x;   // covers 1040*256
    float s = 0.f;
    for (int k = 0; k < splitk; ++k) s += vp[(size_t)k * kNCol * kB + idx];
    v[idx] = s;
}

// W[b] = V1@V2@V3@V4@V5col (right fold); one 64-thr block per batch
__global__ void fttv_chain(const float* __restrict__ v, float* __restrict__ w)
{
    const int b = blockIdx.x;
    const int lane = threadIdx.x;
    const int d = lane & 15;
    float u = v[(size_t)(1024 + d) * kB + b];
    #pragma unroll
    for (int k = 4; k >= 1; --k) {
        float nu = 0.f;
        #pragma unroll
        for (int e = 0; e < 16; ++e) {
            const float ue = __shfl(u, e, 16);
            nu += v[(size_t)((k - 1) * 256 + d * 16 + e) * kB + b] * ue;
        }
        u = nu;
    }
    if (lane < 16) w[b * 16 + d] = u;
}

// out[b,s] = sum_d c0[s,d] * W[b,d]
__global__ __launch_bounds__(256) void fttv_out(
    const float* __restrict__ c0, const float* __restrict__ w,
    float* __restrict__ out)
{
    __shared__ float wl[64][16];
    const int sc = blockIdx.x & 63;
    const int bq = blockIdx.x >> 6;
    const int tid = threadIdx.x;
    const int s = sc * 256 + tid;
    float f0[16];
    #pragma unroll
    for (int q = 0; q < 4; ++q)
        *reinterpret_cast<float4*>(&f0[q * 4]) =
            *reinterpret_cast<const float4*>(c0 + (size_t)s * 16 + q * 4);
    *reinterpret_cast<float4*>(&wl[0][0] + tid * 4) =
        *reinterpret_cast<const float4*>(w + bq * 1024 + tid * 4);
    __syncthreads();
    for (int bb = 0; bb < 64; ++bb) {
        float a = 0.f;
        #pragma unroll
        for (int d = 0; d < 16; ++d) a += f0[d] * wl[bb][d];
        out[(size_t)(bq * 64 + bb) * kS + s] = a;
    }
}

// ---------------------------------------------------------------------------
extern "C" void kernel_launch(void* const* d_in, const int* in_sizes, int n_in,
                              void* d_out, int out_size, void* d_ws, size_t ws_size,
                              hipStream_t stream)
{
    (void)in_sizes; (void)n_in; (void)out_size;
    const float* z  = (const float*)d_in[0];
    const float* c0 = (const float*)d_in[1];
    const float* c1 = (const float*)d_in[2];
    const float* c2 = (const float*)d_in[3];
    const float* c3 = (const float*)d_in[4];
    const float* c4 = (const float*)d_in[5];
    const float* c5 = (const float*)d_in[6];
    float* out = (float*)d_out;
    float* ws  = (float*)d_ws;

    // ws: vp[splitk][1040][256] | v[1040][256] | w[256][16]
    int splitk = 32;
    while (splitk > 1 &&
           ((size_t)(splitk + 1) * kNCol * kB + (size_t)kB * 16) * sizeof(float) > ws_size)
        splitk >>= 1;
    const int kc = kS / splitk;   // kc % 64 == 0 for splitk <= 256

    float* vp = ws;
    float* v  = vp + (size_t)splitk * kNCol * kB;
    float* w  = v + (size_t)kNCol * kB;

    fttv_gemm_mfma<<<dim3(34 * splitk), 256, 0, stream>>>(z, c1, c2, c3, c4, c5, vp, kc);
    fttv_reduce<<<dim3((kNCol * kB) / 256), 256, 0, stream>>>(vp, v, splitk);
    fttv_chain<<<dim3(kB), 64, 0, stream>>>(v, w);
    fttv_out<<<dim3(256), 256, 0, stream>>>(c0, w, out);
}